// Round 3
// baseline (674.158 us; speedup 1.0000x reference)
//
#include <hip/hip_runtime.h>
#include <hip/hip_bf16.h>
#include <stdint.h>

#define FDIM 128
#define CDIM 10

typedef unsigned short u16;

__device__ inline float bf2f(u16 b) {
    return __uint_as_float(((unsigned int)b) << 16);
}
__device__ inline u16 f2bf(float f) {
    unsigned int u = __float_as_uint(f);
    u += 0x7fff + ((u >> 16) & 1);  // round-to-nearest-even
    return (u16)(u >> 16);
}
__device__ inline unsigned int pack2(float a, float b) {
    return (unsigned int)f2bf(a) | ((unsigned int)f2bf(b) << 16);
}

// ---------------- utility ----------------

__global__ void zero_kernel(int* __restrict__ p, int n) {
    int i = blockIdx.x * blockDim.x + threadIdx.x;
    if (i < n) p[i] = 0;
}

__global__ void sentinel_kernel(float* __restrict__ out, int n, float val) {
    int i = blockIdx.x * blockDim.x + threadIdx.x;
    if (i < n) out[i] = val;
}

// ---------------- CSR build ----------------
// NOTE: harness delivers integer inputs as int32 (NOT int64) — edge/batch are const int*.

__global__ void hist_kernel(const int* __restrict__ dst, int E, int* __restrict__ deg) {
    int i = blockIdx.x * blockDim.x + threadIdx.x;
    int stride = gridDim.x * blockDim.x;
    for (; i < E; i += stride) {
        atomicAdd(&deg[dst[i]], 1);
    }
}

// pass1: 1024 elems per block (256 thr x 4), exclusive prefix within block -> rowp, block total -> bsum
__global__ void scan1_kernel(const int* __restrict__ deg, int N,
                             int* __restrict__ rowp, int* __restrict__ bsum) {
    __shared__ int s[256];
    int tid = threadIdx.x;
    int base = blockIdx.x * 1024 + tid * 4;
    int v[4];
#pragma unroll
    for (int j = 0; j < 4; ++j) v[j] = (base + j < N) ? deg[base + j] : 0;
    int t = v[0] + v[1] + v[2] + v[3];
    s[tid] = t;
    __syncthreads();
    for (int off = 1; off < 256; off <<= 1) {
        int x = (tid >= off) ? s[tid - off] : 0;
        __syncthreads();
        s[tid] += x;
        __syncthreads();
    }
    int run = tid ? s[tid - 1] : 0;
#pragma unroll
    for (int j = 0; j < 4; ++j) {
        if (base + j < N) rowp[base + j] = run;
        run += v[j];
    }
    if (tid == 255) bsum[blockIdx.x] = s[255];
}

__global__ void scan2_kernel(int* bsum, int nb) {
    if (threadIdx.x == 0 && blockIdx.x == 0) {
        int run = 0;
        for (int i = 0; i < nb; ++i) { int t = bsum[i]; bsum[i] = run; run += t; }
    }
}

__global__ void scan3_kernel(int* __restrict__ rowp, int* __restrict__ cur,
                             const int* __restrict__ deg, float* __restrict__ dinv,
                             const int* __restrict__ bsum, int N, int E) {
    int i = blockIdx.x * blockDim.x + threadIdx.x;
    if (i < N) {
        int r = rowp[i] + bsum[i >> 10];
        rowp[i] = r;
        cur[i] = r;
        dinv[i] = rsqrtf(1.0f + (float)deg[i]);  // self-loop => deg >= 1 always
    }
    if (blockIdx.x == 0 && threadIdx.x == 0) rowp[N] = E;
}

__global__ void fill_kernel(const int* __restrict__ src, const int* __restrict__ dst,
                            int E, int* __restrict__ cur, int* __restrict__ colx) {
    int i = blockIdx.x * blockDim.x + threadIdx.x;
    int stride = gridDim.x * blockDim.x;
    for (; i < E; i += stride) {
        int s_ = src[i];
        int d_ = dst[i];
        int pos = atomicAdd(&cur[d_], 1);
        colx[pos] = s_;
    }
}

// ---------------- aggregation ----------------
// out[v] = dinv[v]*(dinv[v]*h[v] + sum_{u->v} dinv[u]*h[u]); out is bf16.
// one wave per node; lane holds cols {2*lane, 2*lane+1}

__device__ inline float2 loadrow2(const float* __restrict__ h, size_t idx) {
    return ((const float2*)h)[idx];
}
__device__ inline float2 loadrow2(const u16* __restrict__ h, size_t idx) {
    unsigned int u = ((const unsigned int*)h)[idx];
    float2 r;
    r.x = bf2f((u16)(u & 0xffffu));
    r.y = bf2f((u16)(u >> 16));
    return r;
}

template <typename T>
__global__ __launch_bounds__(256) void agg_kernel(const T* __restrict__ h,
                                                  const float* __restrict__ dinv,
                                                  const int* __restrict__ rowp,
                                                  const int* __restrict__ colx,
                                                  u16* __restrict__ out, int N) {
    int wib = threadIdx.x >> 6;
    int lane = threadIdx.x & 63;
    int v = blockIdx.x * 4 + wib;
    if (v >= N) return;
    v = __builtin_amdgcn_readfirstlane(v);

    float dv = dinv[v];
    float2 xs = loadrow2(h, (size_t)v * 64 + lane);
    float ax = dv * xs.x;
    float ay = dv * xs.y;

    int e = rowp[v];
    int end = rowp[v + 1];
    for (; e + 4 <= end; e += 4) {
        int u0 = colx[e + 0];
        int u1 = colx[e + 1];
        int u2 = colx[e + 2];
        int u3 = colx[e + 3];
        float d0 = dinv[u0], d1 = dinv[u1], d2 = dinv[u2], d3 = dinv[u3];
        float2 a0 = loadrow2(h, (size_t)u0 * 64 + lane);
        float2 a1 = loadrow2(h, (size_t)u1 * 64 + lane);
        float2 a2 = loadrow2(h, (size_t)u2 * 64 + lane);
        float2 a3 = loadrow2(h, (size_t)u3 * 64 + lane);
        ax += d0 * a0.x; ay += d0 * a0.y;
        ax += d1 * a1.x; ay += d1 * a1.y;
        ax += d2 * a2.x; ay += d2 * a2.y;
        ax += d3 * a3.x; ay += d3 * a3.y;
    }
    for (; e < end; ++e) {
        int u = colx[e];
        float du = dinv[u];
        float2 a = loadrow2(h, (size_t)u * 64 + lane);
        ax += du * a.x; ay += du * a.y;
    }
    ((unsigned int*)out)[(size_t)v * 64 + lane] = pack2(dv * ax, dv * ay);
}

// ---------------- GEMM: out = relu(A @ W + b); A bf16 [N,128], W fp32 [128,128], out bf16 ----------------
// block: 256 threads, 64 rows; thread tile 4 rows x 8 cols; A staged in LDS as fp32, W via L1.

__global__ __launch_bounds__(256) void gemm_relu_kernel(const u16* __restrict__ A,
                                                        const float* __restrict__ W,
                                                        const float* __restrict__ bias,
                                                        u16* __restrict__ out, int N) {
    __shared__ float As[64][132];
    int tid = threadIdx.x;
    int row0 = blockIdx.x * 64;

    const uint2* Ap = (const uint2*)A;  // 4 bf16 per uint2
#pragma unroll
    for (int it = 0; it < 8; ++it) {
        int flat = it * 1024 + tid * 4;  // element index within 64x128 tile
        int r = flat >> 7;
        int c = flat & 127;
        float4 f = make_float4(0.f, 0.f, 0.f, 0.f);
        if (row0 + r < N) {
            uint2 u = Ap[(((size_t)(row0 + r)) * FDIM + c) >> 2];
            f.x = bf2f((u16)(u.x & 0xffffu));
            f.y = bf2f((u16)(u.x >> 16));
            f.z = bf2f((u16)(u.y & 0xffffu));
            f.w = bf2f((u16)(u.y >> 16));
        }
        *(float4*)&As[r][c] = f;
    }
    __syncthreads();

    int tx = tid & 15;   // col group: cols tx*8 .. tx*8+7
    int ty = tid >> 4;   // row group: rows ty*4 .. ty*4+3
    float acc[4][8];
#pragma unroll
    for (int r = 0; r < 4; ++r)
#pragma unroll
        for (int c = 0; c < 8; ++c) acc[r][c] = 0.f;

    const float* Wc = W + tx * 8;
    for (int k = 0; k < 128; ++k) {
        float4 w0 = *(const float4*)&Wc[(size_t)k * FDIM];
        float4 w1 = *(const float4*)&Wc[(size_t)k * FDIM + 4];
        float wv[8] = {w0.x, w0.y, w0.z, w0.w, w1.x, w1.y, w1.z, w1.w};
        float av[4] = {As[ty * 4 + 0][k], As[ty * 4 + 1][k], As[ty * 4 + 2][k], As[ty * 4 + 3][k]};
#pragma unroll
        for (int r = 0; r < 4; ++r)
#pragma unroll
            for (int c = 0; c < 8; ++c) acc[r][c] += av[r] * wv[c];
    }

    float bv[8];
#pragma unroll
    for (int c = 0; c < 8; ++c) bv[c] = bias[tx * 8 + c];

    unsigned int* outw = (unsigned int*)out;
#pragma unroll
    for (int r = 0; r < 4; ++r) {
        int row = row0 + ty * 4 + r;
        if (row < N) {
            uint4 o;
            o.x = pack2(fmaxf(acc[r][0] + bv[0], 0.f), fmaxf(acc[r][1] + bv[1], 0.f));
            o.y = pack2(fmaxf(acc[r][2] + bv[2], 0.f), fmaxf(acc[r][3] + bv[3], 0.f));
            o.z = pack2(fmaxf(acc[r][4] + bv[4], 0.f), fmaxf(acc[r][5] + bv[5], 0.f));
            o.w = pack2(fmaxf(acc[r][6] + bv[6], 0.f), fmaxf(acc[r][7] + bv[7], 0.f));
            *(uint4*)&outw[(size_t)row * 64 + tx * 4] = o;
        }
    }
}

// ---------------- pooling + classifier head + log_softmax ----------------
// one block (256 thr) per graph; batch is sorted int32. h is bf16.

__global__ __launch_bounds__(256) void pool_head_kernel(const u16* __restrict__ h,
                                                        const int* __restrict__ batch, int N,
                                                        const float* __restrict__ Wo,
                                                        const float* __restrict__ bo,
                                                        float* __restrict__ out, int G) {
    int g = blockIdx.x;
    int tid = threadIdx.x;
    __shared__ int bounds[2];
    __shared__ float red[256];
    __shared__ float sp[128];
    __shared__ float lg[CDIM];
    __shared__ float sm[2];

    if (tid < 2) {
        int target = g + tid;
        int lo = 0, hi = N;
        while (lo < hi) {
            int mid = (lo + hi) >> 1;
            if (batch[mid] < target) lo = mid + 1; else hi = mid;
        }
        bounds[tid] = lo;
    }
    __syncthreads();
    int lo = bounds[0], hi = bounds[1];
    int cnt = hi - lo;

    int j = tid & 127;
    int rr = tid >> 7;  // 0 or 1: two rows in flight
    float acc = 0.f;
    for (int r = lo + rr; r < hi; r += 2) acc += bf2f(h[(size_t)r * FDIM + j]);
    red[tid] = acc;
    __syncthreads();
    if (tid < 128) sp[tid] = (red[tid] + red[tid + 128]) / (float)max(cnt, 1);
    __syncthreads();

    if (tid < CDIM) {
        float l = bo[tid];
        for (int k = 0; k < 128; ++k) l += sp[k] * Wo[(size_t)k * CDIM + tid];
        lg[tid] = l;
    }
    __syncthreads();
    if (tid == 0) {
        float m = -1e30f;
        for (int c = 0; c < CDIM; ++c) m = fmaxf(m, lg[c]);
        float ssum = 0.f;
        for (int c = 0; c < CDIM; ++c) ssum += expf(lg[c] - m);
        sm[0] = m;
        sm[1] = logf(ssum);
    }
    __syncthreads();
    if (tid < CDIM) out[(size_t)g * CDIM + tid] = lg[tid] - sm[0] - sm[1];
}

// ---------------- launch ----------------

extern "C" void kernel_launch(void* const* d_in, const int* in_sizes, int n_in,
                              void* d_out, int out_size, void* d_ws, size_t ws_size,
                              hipStream_t stream) {
    const float* x = (const float*)d_in[0];
    const int* edge = (const int*)d_in[1];      // int32! (harness converts integer inputs)
    const int* batch = (const int*)d_in[2];     // int32!
    const float* W1 = (const float*)d_in[4];
    const float* b1 = (const float*)d_in[5];
    const float* W2 = (const float*)d_in[6];
    const float* b2 = (const float*)d_in[7];
    const float* W3 = (const float*)d_in[8];
    const float* b3 = (const float*)d_in[9];
    const float* Wo = (const float*)d_in[10];
    const float* bo = (const float*)d_in[11];

    int N = in_sizes[2];
    int E = in_sizes[1] / 2;
    int G = out_size / CDIM;
    const int* src = edge;
    const int* dst = edge + E;

    // ---- workspace layout (bf16 intermediates: ~59 MB total) ----
    int nb = (N + 1023) / 1024;
    size_t off = 0;
    auto carve = [&](size_t bytes) -> size_t {
        size_t r = off;
        off += (bytes + 255) & ~(size_t)255;
        return r;
    };
    size_t o_aggb = carve((size_t)N * FDIM * 2);   // bf16
    size_t o_hbuf = carve((size_t)N * FDIM * 2);   // bf16
    size_t o_colx = carve((size_t)E * 4);
    size_t o_rowp = carve((size_t)(N + 1) * 4);
    size_t o_cur  = carve((size_t)N * 4);
    size_t o_deg  = carve((size_t)N * 4);
    size_t o_dinv = carve((size_t)N * 4);
    size_t o_bsum = carve((size_t)nb * 4);

    if (off > ws_size) {
        sentinel_kernel<<<(out_size + 255) / 256, 256, 0, stream>>>((float*)d_out, out_size, 1234.5f);
        return;
    }

    char* base = (char*)d_ws;
    u16* aggb = (u16*)(base + o_aggb);
    u16* hbuf = (u16*)(base + o_hbuf);
    int* colx = (int*)(base + o_colx);
    int* rowp = (int*)(base + o_rowp);
    int* cur  = (int*)(base + o_cur);
    int* deg  = (int*)(base + o_deg);
    float* dinv = (float*)(base + o_dinv);
    int* bsum = (int*)(base + o_bsum);

    zero_kernel<<<(N + 255) / 256, 256, 0, stream>>>(deg, N);
    hist_kernel<<<2048, 256, 0, stream>>>(dst, E, deg);
    scan1_kernel<<<nb, 256, 0, stream>>>(deg, N, rowp, bsum);
    scan2_kernel<<<1, 64, 0, stream>>>(bsum, nb);
    scan3_kernel<<<(N + 255) / 256, 256, 0, stream>>>(rowp, cur, deg, dinv, bsum, N, E);
    fill_kernel<<<2048, 256, 0, stream>>>(src, dst, E, cur, colx);

    int aggBlocks = (N + 3) / 4;
    int gemmBlocks = (N + 63) / 64;

    // layer 1 (reads fp32 x)
    agg_kernel<float><<<aggBlocks, 256, 0, stream>>>(x, dinv, rowp, colx, aggb, N);
    gemm_relu_kernel<<<gemmBlocks, 256, 0, stream>>>(aggb, W1, b1, hbuf, N);
    // layer 2
    agg_kernel<u16><<<aggBlocks, 256, 0, stream>>>(hbuf, dinv, rowp, colx, aggb, N);
    gemm_relu_kernel<<<gemmBlocks, 256, 0, stream>>>(aggb, W2, b2, hbuf, N);
    // layer 3
    agg_kernel<u16><<<aggBlocks, 256, 0, stream>>>(hbuf, dinv, rowp, colx, aggb, N);
    gemm_relu_kernel<<<gemmBlocks, 256, 0, stream>>>(aggb, W3, b3, hbuf, N);

    pool_head_kernel<<<G, 256, 0, stream>>>(hbuf, batch, N, Wo, bo, (float*)d_out, G);
}

// Round 4
// 454.454 us; speedup vs baseline: 1.4834x; 1.4834x over previous
//
#include <hip/hip_runtime.h>
#include <hip/hip_bf16.h>
#include <stdint.h>

#define FDIM 128
#define CDIM 10

typedef unsigned short u16;
typedef __attribute__((ext_vector_type(8))) short short8;   // 8 bf16 (4 VGPRs) — MFMA A/B frag
typedef __attribute__((ext_vector_type(4))) float f32x4;    // MFMA C/D frag

__device__ inline float bf2f(u16 b) {
    return __uint_as_float(((unsigned int)b) << 16);
}
__device__ inline u16 f2bf(float f) {
    unsigned int u = __float_as_uint(f);
    u += 0x7fff + ((u >> 16) & 1);  // round-to-nearest-even
    return (u16)(u >> 16);
}
__device__ inline unsigned int pack2(float a, float b) {
    return (unsigned int)f2bf(a) | ((unsigned int)f2bf(b) << 16);
}

// ---------------- utility ----------------

__global__ void zero_kernel(int* __restrict__ p, int n) {
    int i = blockIdx.x * blockDim.x + threadIdx.x;
    if (i < n) p[i] = 0;
}

__global__ void sentinel_kernel(float* __restrict__ out, int n, float val) {
    int i = blockIdx.x * blockDim.x + threadIdx.x;
    if (i < n) out[i] = val;
}

// W [128][128] fp32 -> WbT [n][k] bf16 (transposed), for 3 weight matrices
__global__ void wconv_kernel(const float* __restrict__ W1, const float* __restrict__ W2,
                             const float* __restrict__ W3, u16* __restrict__ wbt) {
    int which = blockIdx.x >> 6;                 // 64 blocks per matrix
    int i = (blockIdx.x & 63) * 256 + threadIdx.x;  // 0..16383
    const float* W = which == 0 ? W1 : (which == 1 ? W2 : W3);
    int k = i >> 7, n = i & 127;
    wbt[(size_t)which * 16384 + n * 128 + k] = f2bf(W[k * 128 + n]);
}

// ---------------- bucketed CSR build ----------------
// buckets of 256 nodes: b = dst >> 8.  NB = ceil(N/256) <= 512.

__global__ __launch_bounds__(256) void count_kernel(const int* __restrict__ dst, int E,
                                                    int* __restrict__ bcnt, int NB) {
    __shared__ int lc[512];
    int tid = threadIdx.x;
    for (int i = tid; i < NB; i += 256) lc[i] = 0;
    __syncthreads();
    int base = blockIdx.x * 4096;
    int lim = min(base + 4096, E);
    for (int i = base + tid; i < lim; i += 256)
        atomicAdd(&lc[dst[i] >> 8], 1);
    __syncthreads();
    for (int i = tid; i < NB; i += 256)
        if (lc[i]) atomicAdd(&bcnt[i], lc[i]);
}

__global__ __launch_bounds__(512) void scan_kernel(const int* __restrict__ bcnt, int NB, int E,
                                                   int* __restrict__ boff, int* __restrict__ bcursor) {
    __shared__ int s[512];
    int tid = threadIdx.x;
    s[tid] = (tid < NB) ? bcnt[tid] : 0;
    __syncthreads();
    for (int off = 1; off < 512; off <<= 1) {
        int v = (tid >= off) ? s[tid - off] : 0;
        __syncthreads();
        s[tid] += v;
        __syncthreads();
    }
    int excl = tid ? s[tid - 1] : 0;
    if (tid < NB) { boff[tid] = excl; bcursor[tid] = excl; }
    if (tid == 0) boff[NB] = E;
}

__global__ __launch_bounds__(256) void part_kernel(const int* __restrict__ src,
                                                   const int* __restrict__ dst, int E,
                                                   int* __restrict__ bcursor,
                                                   uint2* __restrict__ ebuf, int NB) {
    __shared__ int lc[512];
    __shared__ int lbase[512];
    int tid = threadIdx.x;
    for (int i = tid; i < NB; i += 256) lc[i] = 0;
    __syncthreads();
    int base = blockIdx.x * 4096;
    int lim = min(base + 4096, E);
    for (int i = base + tid; i < lim; i += 256)
        atomicAdd(&lc[dst[i] >> 8], 1);
    __syncthreads();
    for (int i = tid; i < NB; i += 256) {
        int c = lc[i];
        lbase[i] = c ? atomicAdd(&bcursor[i], c) : 0;
        lc[i] = 0;  // reuse as local cursor
    }
    __syncthreads();
    for (int i = base + tid; i < lim; i += 256) {
        int s_ = src[i];
        int d_ = dst[i];
        int b = d_ >> 8;
        int r = atomicAdd(&lc[b], 1);
        ebuf[lbase[b] + r] = make_uint2((unsigned)s_, (unsigned)d_);
    }
}

// one block per bucket: local hist -> scan -> rowp/deg/dinv; scatter colx within bucket window
__global__ __launch_bounds__(256) void build_kernel(const uint2* __restrict__ ebuf,
                                                    const int* __restrict__ boff,
                                                    int* __restrict__ rowp, float* __restrict__ dinv,
                                                    int* __restrict__ colx, int N, int E) {
    __shared__ int hist[256];
    __shared__ int pfx[256];
    __shared__ int cur[256];
    int b = blockIdx.x;
    int tid = threadIdx.x;
    int ebase = boff[b], eend = boff[b + 1];
    hist[tid] = 0;
    __syncthreads();
    for (int i = ebase + tid; i < eend; i += 256)
        atomicAdd(&hist[ebuf[i].y & 255], 1);
    __syncthreads();
    int deg = hist[tid];
    pfx[tid] = deg;
    __syncthreads();
    for (int off = 1; off < 256; off <<= 1) {
        int t = (tid >= off) ? pfx[tid - off] : 0;
        __syncthreads();
        pfx[tid] += t;
        __syncthreads();
    }
    int excl = pfx[tid] - deg;
    int node = b * 256 + tid;
    if (node < N) {
        rowp[node] = ebase + excl;
        dinv[node] = rsqrtf(1.0f + (float)deg);  // +1 self-loop
        if (node == N - 1) rowp[N] = E;
    }
    cur[tid] = ebase + excl;
    __syncthreads();
    for (int i = ebase + tid; i < eend; i += 256) {
        uint2 e = ebuf[i];
        int r = atomicAdd(&cur[e.y & 255], 1);
        colx[r] = (int)e.x;
    }
}

// ---------------- aggregation ----------------
// out[v] = dinv[v]*(dinv[v]*h[v] + sum_{u->v} dinv[u]*h[u]); out is bf16.

__device__ inline float2 loadrow2(const float* __restrict__ h, size_t idx) {
    return ((const float2*)h)[idx];
}
__device__ inline float2 loadrow2(const u16* __restrict__ h, size_t idx) {
    unsigned int u = ((const unsigned int*)h)[idx];
    float2 r;
    r.x = bf2f((u16)(u & 0xffffu));
    r.y = bf2f((u16)(u >> 16));
    return r;
}

template <typename T>
__global__ __launch_bounds__(256) void agg_kernel(const T* __restrict__ h,
                                                  const float* __restrict__ dinv,
                                                  const int* __restrict__ rowp,
                                                  const int* __restrict__ colx,
                                                  u16* __restrict__ out, int N) {
    int wib = threadIdx.x >> 6;
    int lane = threadIdx.x & 63;
    int v = blockIdx.x * 4 + wib;
    if (v >= N) return;
    v = __builtin_amdgcn_readfirstlane(v);

    float dv = dinv[v];
    float2 xs = loadrow2(h, (size_t)v * 64 + lane);
    float ax = dv * xs.x;
    float ay = dv * xs.y;

    int e = rowp[v];
    int end = rowp[v + 1];
    for (; e + 4 <= end; e += 4) {
        int u0 = colx[e + 0];
        int u1 = colx[e + 1];
        int u2 = colx[e + 2];
        int u3 = colx[e + 3];
        float d0 = dinv[u0], d1 = dinv[u1], d2 = dinv[u2], d3 = dinv[u3];
        float2 a0 = loadrow2(h, (size_t)u0 * 64 + lane);
        float2 a1 = loadrow2(h, (size_t)u1 * 64 + lane);
        float2 a2 = loadrow2(h, (size_t)u2 * 64 + lane);
        float2 a3 = loadrow2(h, (size_t)u3 * 64 + lane);
        ax += d0 * a0.x; ay += d0 * a0.y;
        ax += d1 * a1.x; ay += d1 * a1.y;
        ax += d2 * a2.x; ay += d2 * a2.y;
        ax += d3 * a3.x; ay += d3 * a3.y;
    }
    for (; e < end; ++e) {
        int u = colx[e];
        float du = dinv[u];
        float2 a = loadrow2(h, (size_t)u * 64 + lane);
        ax += du * a.x; ay += du * a.y;
    }
    ((unsigned int*)out)[(size_t)v * 64 + lane] = pack2(dv * ax, dv * ay);
}

// ---------------- MFMA GEMM: out = relu(A @ W + b) ----------------
// A bf16 [N,128]; WbT bf16 [n][k] (W transposed); out bf16. 4 waves/block, 64 rows/block.
// v_mfma_f32_16x16x32_bf16: A lane l holds A[l&15][8*(l>>4)+e]; B lane l holds B[8*(l>>4)+e][l&15];
// C/D lane l holds C[(l>>4)*4+r][l&15]  (guide §3, m89-verified).

__global__ __launch_bounds__(256) void gemm_mfma_kernel(const u16* __restrict__ A,
                                                        const u16* __restrict__ WbT,
                                                        const float* __restrict__ bias,
                                                        u16* __restrict__ out, int N) {
    __shared__ u16 As[64][136];  // 272B rows: 16B-aligned, 2-way bank alias only
    int tid = threadIdx.x;
    int w = tid >> 6;
    int l = tid & 63;
    int row0 = blockIdx.x * 64;

    // stage A tile: 1024 chunks of 16B; thread handles 4
#pragma unroll
    for (int i = 0; i < 4; ++i) {
        int c = tid + 256 * i;
        int r = c >> 4;
        int col = (c & 15) * 8;
        uint4 val = make_uint4(0, 0, 0, 0);
        if (row0 + r < N) val = *(const uint4*)&A[(size_t)(row0 + r) * FDIM + col];
        *(uint4*)&As[r][col] = val;
    }
    __syncthreads();

    int arow = w * 16 + (l & 15);
    int kblk = (l >> 4) * 8;
    f32x4 acc[8];
#pragma unroll
    for (int f = 0; f < 8; ++f) acc[f] = (f32x4){0.f, 0.f, 0.f, 0.f};

#pragma unroll
    for (int kk = 0; kk < 4; ++kk) {
        int k0 = kk * 32 + kblk;
        short8 a = *(const short8*)&As[arow][k0];
#pragma unroll
        for (int f = 0; f < 8; ++f) {
            int col = f * 16 + (l & 15);
            short8 bfr = *(const short8*)&WbT[(size_t)col * FDIM + k0];
            acc[f] = __builtin_amdgcn_mfma_f32_16x16x32_bf16(a, bfr, acc[f], 0, 0, 0);
        }
    }

    int rbase = w * 16 + (l >> 4) * 4;
    int cidx = l & 15;
#pragma unroll
    for (int f = 0; f < 8; ++f) {
        int col = f * 16 + cidx;
        float bv = bias[col];
#pragma unroll
        for (int r = 0; r < 4; ++r) {
            int row = row0 + rbase + r;
            if (row < N) out[(size_t)row * FDIM + col] = f2bf(fmaxf(acc[f][r] + bv, 0.f));
        }
    }
}

// ---------------- pooling + classifier head + log_softmax ----------------

__global__ __launch_bounds__(256) void pool_head_kernel(const u16* __restrict__ h,
                                                        const int* __restrict__ batch, int N,
                                                        const float* __restrict__ Wo,
                                                        const float* __restrict__ bo,
                                                        float* __restrict__ out, int G) {
    int g = blockIdx.x;
    int tid = threadIdx.x;
    __shared__ int bounds[2];
    __shared__ float red[256];
    __shared__ float sp[128];
    __shared__ float lg[CDIM];
    __shared__ float sm[2];

    if (tid < 2) {
        int target = g + tid;
        int lo = 0, hi = N;
        while (lo < hi) {
            int mid = (lo + hi) >> 1;
            if (batch[mid] < target) lo = mid + 1; else hi = mid;
        }
        bounds[tid] = lo;
    }
    __syncthreads();
    int lo = bounds[0], hi = bounds[1];
    int cnt = hi - lo;

    int j = tid & 127;
    int rr = tid >> 7;
    float acc = 0.f;
    for (int r = lo + rr; r < hi; r += 2) acc += bf2f(h[(size_t)r * FDIM + j]);
    red[tid] = acc;
    __syncthreads();
    if (tid < 128) sp[tid] = (red[tid] + red[tid + 128]) / (float)max(cnt, 1);
    __syncthreads();

    if (tid < CDIM) {
        float l = bo[tid];
        for (int k = 0; k < 128; ++k) l += sp[k] * Wo[(size_t)k * CDIM + tid];
        lg[tid] = l;
    }
    __syncthreads();
    if (tid == 0) {
        float m = -1e30f;
        for (int c = 0; c < CDIM; ++c) m = fmaxf(m, lg[c]);
        float ssum = 0.f;
        for (int c = 0; c < CDIM; ++c) ssum += expf(lg[c] - m);
        sm[0] = m;
        sm[1] = logf(ssum);
    }
    __syncthreads();
    if (tid < CDIM) out[(size_t)g * CDIM + tid] = lg[tid] - sm[0] - sm[1];
}

// ---------------- launch ----------------

extern "C" void kernel_launch(void* const* d_in, const int* in_sizes, int n_in,
                              void* d_out, int out_size, void* d_ws, size_t ws_size,
                              hipStream_t stream) {
    const float* x = (const float*)d_in[0];
    const int* edge = (const int*)d_in[1];      // int32 (harness converts integer inputs)
    const int* batch = (const int*)d_in[2];     // int32
    const float* W1 = (const float*)d_in[4];
    const float* b1 = (const float*)d_in[5];
    const float* W2 = (const float*)d_in[6];
    const float* b2 = (const float*)d_in[7];
    const float* W3 = (const float*)d_in[8];
    const float* b3 = (const float*)d_in[9];
    const float* Wo = (const float*)d_in[10];
    const float* bo = (const float*)d_in[11];

    int N = in_sizes[2];
    int E = in_sizes[1] / 2;
    int G = out_size / CDIM;
    const int* src = edge;
    const int* dst = edge + E;
    int NB = (N + 255) >> 8;   // buckets of 256 nodes

    size_t off = 0;
    auto carve = [&](size_t bytes) -> size_t {
        size_t r = off;
        off += (bytes + 255) & ~(size_t)255;
        return r;
    };
    size_t o_aggb = carve((size_t)N * FDIM * 2);    // bf16
    size_t o_hbuf = carve((size_t)N * FDIM * 2);    // bf16 (ebuf aliased here during CSR build)
    size_t o_colx = carve((size_t)E * 4);
    size_t o_rowp = carve((size_t)(N + 1) * 4);
    size_t o_dinv = carve((size_t)N * 4);
    size_t o_bcnt = carve((size_t)NB * 4);
    size_t o_boff = carve((size_t)(NB + 1) * 4);
    size_t o_bcur = carve((size_t)NB * 4);
    size_t o_wbt  = carve((size_t)3 * 16384 * 2);   // 3x bf16 W^T

    if (off > ws_size || NB > 512 || (size_t)E * 8 > (size_t)N * FDIM * 2) {
        sentinel_kernel<<<(out_size + 255) / 256, 256, 0, stream>>>((float*)d_out, out_size, 1234.5f);
        return;
    }

    char* base = (char*)d_ws;
    u16* aggb  = (u16*)(base + o_aggb);
    u16* hbuf  = (u16*)(base + o_hbuf);
    uint2* ebuf = (uint2*)(base + o_hbuf);   // alias: dead before first gemm writes hbuf
    int* colx  = (int*)(base + o_colx);
    int* rowp  = (int*)(base + o_rowp);
    float* dinv = (float*)(base + o_dinv);
    int* bcnt  = (int*)(base + o_bcnt);
    int* boff  = (int*)(base + o_boff);
    int* bcur  = (int*)(base + o_bcur);
    u16* wbt   = (u16*)(base + o_wbt);

    int nchunk = (E + 4095) / 4096;

    wconv_kernel<<<192, 256, 0, stream>>>(W1, W2, W3, wbt);
    zero_kernel<<<1, 512, 0, stream>>>(bcnt, NB);
    count_kernel<<<nchunk, 256, 0, stream>>>(dst, E, bcnt, NB);
    scan_kernel<<<1, 512, 0, stream>>>(bcnt, NB, E, boff, bcur);
    part_kernel<<<nchunk, 256, 0, stream>>>(src, dst, E, bcur, ebuf, NB);
    build_kernel<<<NB, 256, 0, stream>>>(ebuf, boff, rowp, dinv, colx, N, E);

    int aggBlocks = (N + 3) / 4;
    int gemmBlocks = (N + 63) / 64;

    agg_kernel<float><<<aggBlocks, 256, 0, stream>>>(x, dinv, rowp, colx, aggb, N);
    gemm_mfma_kernel<<<gemmBlocks, 256, 0, stream>>>(aggb, wbt, b1, hbuf, N);
    agg_kernel<u16><<<aggBlocks, 256, 0, stream>>>(hbuf, dinv, rowp, colx, aggb, N);
    gemm_mfma_kernel<<<gemmBlocks, 256, 0, stream>>>(aggb, wbt + 16384, b2, hbuf, N);
    agg_kernel<u16><<<aggBlocks, 256, 0, stream>>>(hbuf, dinv, rowp, colx, aggb, N);
    gemm_mfma_kernel<<<gemmBlocks, 256, 0, stream>>>(aggb, wbt + 32768, b3, hbuf, N);

    pool_head_kernel<<<G, 256, 0, stream>>>(hbuf, batch, N, Wo, bo, (float*)d_out, G);
}

// Round 5
// 413.175 us; speedup vs baseline: 1.6317x; 1.0999x over previous
//
#include <hip/hip_runtime.h>
#include <hip/hip_bf16.h>
#include <stdint.h>

#define FDIM 128
#define CDIM 10

typedef unsigned short u16;
typedef __attribute__((ext_vector_type(8))) short short8;   // 8 bf16 (4 VGPRs) — MFMA A/B frag
typedef __attribute__((ext_vector_type(4))) float f32x4;    // MFMA C/D frag

__device__ inline float bf2f(u16 b) {
    return __uint_as_float(((unsigned int)b) << 16);
}
__device__ inline u16 f2bf(float f) {
    unsigned int u = __float_as_uint(f);
    u += 0x7fff + ((u >> 16) & 1);  // round-to-nearest-even
    return (u16)(u >> 16);
}
__device__ inline unsigned int pack2(float a, float b) {
    return (unsigned int)f2bf(a) | ((unsigned int)f2bf(b) << 16);
}
// acc[0] += d*lo_bf16(u); acc[1] += d*hi_bf16(u)
__device__ inline void fma_bf2(float* acc, float d, unsigned int u) {
    acc[0] = fmaf(d, __uint_as_float(u << 16), acc[0]);
    acc[1] = fmaf(d, __uint_as_float(u & 0xffff0000u), acc[1]);
}

// ---------------- utility ----------------

__global__ void zero_kernel(int* __restrict__ p, int n) {
    int i = blockIdx.x * blockDim.x + threadIdx.x;
    if (i < n) p[i] = 0;
}

__global__ void sentinel_kernel(float* __restrict__ out, int n, float val) {
    int i = blockIdx.x * blockDim.x + threadIdx.x;
    if (i < n) out[i] = val;
}

// W [128][128] fp32 -> WbT [n][k] bf16 (transposed), for 3 weight matrices
__global__ void wconv_kernel(const float* __restrict__ W1, const float* __restrict__ W2,
                             const float* __restrict__ W3, u16* __restrict__ wbt) {
    int which = blockIdx.x >> 6;
    int i = (blockIdx.x & 63) * 256 + threadIdx.x;
    const float* W = which == 0 ? W1 : (which == 1 ? W2 : W3);
    int k = i >> 7, n = i & 127;
    wbt[(size_t)which * 16384 + n * 128 + k] = f2bf(W[k * 128 + n]);
}

// x fp32 -> bf16 (4 elems/thread)
__global__ void xconv_kernel(const float* __restrict__ x, u16* __restrict__ xb, int total) {
    int i = (blockIdx.x * blockDim.x + threadIdx.x) * 4;
    if (i < total) {
        float4 f = *(const float4*)&x[i];
        uint2 o;
        o.x = pack2(f.x, f.y);
        o.y = pack2(f.z, f.w);
        *(uint2*)&xb[i] = o;
    }
}

// ---------------- bucketed CSR build ----------------
// buckets of 256 nodes: b = dst >> 8.  NB = ceil(N/256) <= 512.
// ebuf entry packed: (dst & 255) << 24 | src   (requires N <= 2^24)

__global__ __launch_bounds__(256) void count_kernel(const int* __restrict__ dst, int E,
                                                    int* __restrict__ bcnt, int NB) {
    __shared__ int lc[512];
    int tid = threadIdx.x;
    for (int i = tid; i < NB; i += 256) lc[i] = 0;
    __syncthreads();
    int base = blockIdx.x * 4096;
    int lim = min(base + 4096, E);
    for (int i = base + tid; i < lim; i += 256)
        atomicAdd(&lc[dst[i] >> 8], 1);
    __syncthreads();
    for (int i = tid; i < NB; i += 256)
        if (lc[i]) atomicAdd(&bcnt[i], lc[i]);
}

__global__ __launch_bounds__(512) void scan_kernel(const int* __restrict__ bcnt, int NB, int E,
                                                   int* __restrict__ boff, int* __restrict__ bcursor) {
    __shared__ int s[512];
    int tid = threadIdx.x;
    s[tid] = (tid < NB) ? bcnt[tid] : 0;
    __syncthreads();
    for (int off = 1; off < 512; off <<= 1) {
        int v = (tid >= off) ? s[tid - off] : 0;
        __syncthreads();
        s[tid] += v;
        __syncthreads();
    }
    int excl = tid ? s[tid - 1] : 0;
    if (tid < NB) { boff[tid] = excl; bcursor[tid] = excl; }
    if (tid == 0) boff[NB] = E;
}

__global__ __launch_bounds__(256) void part_kernel(const int* __restrict__ src,
                                                   const int* __restrict__ dst, int E,
                                                   int* __restrict__ bcursor,
                                                   unsigned* __restrict__ ebuf, int NB) {
    __shared__ int lc[512];
    __shared__ int lbase[512];
    int tid = threadIdx.x;
    for (int i = tid; i < NB; i += 256) lc[i] = 0;
    __syncthreads();
    int base = blockIdx.x * 4096;
    int lim = min(base + 4096, E);
    for (int i = base + tid; i < lim; i += 256)
        atomicAdd(&lc[dst[i] >> 8], 1);
    __syncthreads();
    for (int i = tid; i < NB; i += 256) {
        int c = lc[i];
        lbase[i] = c ? atomicAdd(&bcursor[i], c) : 0;
        lc[i] = 0;  // reuse as local cursor
    }
    __syncthreads();
    for (int i = base + tid; i < lim; i += 256) {
        int s_ = src[i];
        int d_ = dst[i];
        int b = d_ >> 8;
        int r = atomicAdd(&lc[b], 1);
        ebuf[lbase[b] + r] = ((unsigned)(d_ & 255) << 24) | (unsigned)s_;
    }
}

// one block per bucket: local hist -> scan -> rowp/deg/dinv; scatter colx within bucket window
__global__ __launch_bounds__(256) void build_kernel(const unsigned* __restrict__ ebuf,
                                                    const int* __restrict__ boff,
                                                    int* __restrict__ rowp, float* __restrict__ dinv,
                                                    int* __restrict__ colx, int N, int E) {
    __shared__ int hist[256];
    __shared__ int pfx[256];
    __shared__ int cur[256];
    int b = blockIdx.x;
    int tid = threadIdx.x;
    int ebase = boff[b], eend = boff[b + 1];
    hist[tid] = 0;
    __syncthreads();
    for (int i = ebase + tid; i < eend; i += 256)
        atomicAdd(&hist[ebuf[i] >> 24], 1);
    __syncthreads();
    int deg = hist[tid];
    pfx[tid] = deg;
    __syncthreads();
    for (int off = 1; off < 256; off <<= 1) {
        int t = (tid >= off) ? pfx[tid - off] : 0;
        __syncthreads();
        pfx[tid] += t;
        __syncthreads();
    }
    int excl = pfx[tid] - deg;
    int node = b * 256 + tid;
    if (node < N) {
        rowp[node] = ebase + excl;
        dinv[node] = rsqrtf(1.0f + (float)deg);  // +1 self-loop
        if (node == N - 1) rowp[N] = E;
    }
    cur[tid] = ebase + excl;
    __syncthreads();
    for (int i = ebase + tid; i < eend; i += 256) {
        unsigned e = ebuf[i];
        int r = atomicAdd(&cur[e >> 24], 1);
        colx[r] = (int)(e & 0xFFFFFFu);
    }
}

// ---------------- aggregation ----------------
// out[v] = dinv[v]*(dinv[v]*h[v] + sum_{u->v} dinv[u]*h[u]); h,out bf16.
// wave geometry: lane = 16*g + c; group g processes edge e+g; lane covers cols [8c,8c+8) (16B).
// 8 row-gathers in flight per wave (unroll 2 x 4 groups); cross-group combine via shfl_xor.

__global__ __launch_bounds__(256) void agg_kernel(const u16* __restrict__ h,
                                                  const float* __restrict__ dinv,
                                                  const int* __restrict__ rowp,
                                                  const int* __restrict__ colx,
                                                  u16* __restrict__ out, int N) {
    int wib = threadIdx.x >> 6;
    int lane = threadIdx.x & 63;
    int g = lane >> 4;
    int c = lane & 15;
    int v = blockIdx.x * 4 + wib;
    if (v >= N) return;
    v = __builtin_amdgcn_readfirstlane(v);

    const uint4* h4 = (const uint4*)h;
    float dv = dinv[v];
    uint4 self = h4[(size_t)v * 16 + c];

    float acc[8];
#pragma unroll
    for (int j = 0; j < 8; ++j) acc[j] = 0.f;

    int e0 = rowp[v], end = rowp[v + 1];
    for (int e = e0; e < end; e += 8) {
        int ea = e + g, eb = e + 4 + g;
        int ia = min(ea, end - 1);
        int ib = min(eb, end - 1);
        int ua = colx[ia];
        int ub = colx[ib];
        float da = (ea < end) ? dinv[ua] : 0.f;
        float db = (eb < end) ? dinv[ub] : 0.f;
        uint4 ra = h4[(size_t)ua * 16 + c];
        uint4 rb = h4[(size_t)ub * 16 + c];
        fma_bf2(acc + 0, da, ra.x);
        fma_bf2(acc + 2, da, ra.y);
        fma_bf2(acc + 4, da, ra.z);
        fma_bf2(acc + 6, da, ra.w);
        fma_bf2(acc + 0, db, rb.x);
        fma_bf2(acc + 2, db, rb.y);
        fma_bf2(acc + 4, db, rb.z);
        fma_bf2(acc + 6, db, rb.w);
    }

#pragma unroll
    for (int j = 0; j < 8; ++j) {
        acc[j] += __shfl_xor(acc[j], 16, 64);
        acc[j] += __shfl_xor(acc[j], 32, 64);
    }

    if (g == 0) {
        float s0 = __uint_as_float(self.x << 16);
        float s1 = __uint_as_float(self.x & 0xffff0000u);
        float s2 = __uint_as_float(self.y << 16);
        float s3 = __uint_as_float(self.y & 0xffff0000u);
        float s4 = __uint_as_float(self.z << 16);
        float s5 = __uint_as_float(self.z & 0xffff0000u);
        float s6 = __uint_as_float(self.w << 16);
        float s7 = __uint_as_float(self.w & 0xffff0000u);
        uint4 o;
        o.x = pack2(dv * (acc[0] + dv * s0), dv * (acc[1] + dv * s1));
        o.y = pack2(dv * (acc[2] + dv * s2), dv * (acc[3] + dv * s3));
        o.z = pack2(dv * (acc[4] + dv * s4), dv * (acc[5] + dv * s5));
        o.w = pack2(dv * (acc[6] + dv * s6), dv * (acc[7] + dv * s7));
        ((uint4*)out)[(size_t)v * 16 + c] = o;
    }
}

// ---------------- MFMA GEMM: out = relu(A @ W + b) ----------------

__global__ __launch_bounds__(256) void gemm_mfma_kernel(const u16* __restrict__ A,
                                                        const u16* __restrict__ WbT,
                                                        const float* __restrict__ bias,
                                                        u16* __restrict__ out, int N) {
    __shared__ u16 As[64][136];
    int tid = threadIdx.x;
    int w = tid >> 6;
    int l = tid & 63;
    int row0 = blockIdx.x * 64;

#pragma unroll
    for (int i = 0; i < 4; ++i) {
        int c = tid + 256 * i;
        int r = c >> 4;
        int col = (c & 15) * 8;
        uint4 val = make_uint4(0, 0, 0, 0);
        if (row0 + r < N) val = *(const uint4*)&A[(size_t)(row0 + r) * FDIM + col];
        *(uint4*)&As[r][col] = val;
    }
    __syncthreads();

    int arow = w * 16 + (l & 15);
    int kblk = (l >> 4) * 8;
    f32x4 acc[8];
#pragma unroll
    for (int f = 0; f < 8; ++f) acc[f] = (f32x4){0.f, 0.f, 0.f, 0.f};

#pragma unroll
    for (int kk = 0; kk < 4; ++kk) {
        int k0 = kk * 32 + kblk;
        short8 a = *(const short8*)&As[arow][k0];
#pragma unroll
        for (int f = 0; f < 8; ++f) {
            int col = f * 16 + (l & 15);
            short8 bfr = *(const short8*)&WbT[(size_t)col * FDIM + k0];
            acc[f] = __builtin_amdgcn_mfma_f32_16x16x32_bf16(a, bfr, acc[f], 0, 0, 0);
        }
    }

    int rbase = w * 16 + (l >> 4) * 4;
    int cidx = l & 15;
#pragma unroll
    for (int f = 0; f < 8; ++f) {
        int col = f * 16 + cidx;
        float bv = bias[col];
#pragma unroll
        for (int r = 0; r < 4; ++r) {
            int row = row0 + rbase + r;
            if (row < N) out[(size_t)row * FDIM + col] = f2bf(fmaxf(acc[f][r] + bv, 0.f));
        }
    }
}

// ---------------- pooling + classifier head + log_softmax ----------------

__global__ __launch_bounds__(256) void pool_head_kernel(const u16* __restrict__ h,
                                                        const int* __restrict__ batch, int N,
                                                        const float* __restrict__ Wo,
                                                        const float* __restrict__ bo,
                                                        float* __restrict__ out, int G) {
    int g = blockIdx.x;
    int tid = threadIdx.x;
    __shared__ int bounds[2];
    __shared__ float red[256];
    __shared__ float sp[128];
    __shared__ float lg[CDIM];
    __shared__ float sm[2];

    if (tid < 2) {
        int target = g + tid;
        int lo = 0, hi = N;
        while (lo < hi) {
            int mid = (lo + hi) >> 1;
            if (batch[mid] < target) lo = mid + 1; else hi = mid;
        }
        bounds[tid] = lo;
    }
    __syncthreads();
    int lo = bounds[0], hi = bounds[1];
    int cnt = hi - lo;

    int j = tid & 127;
    int rr = tid >> 7;
    float acc = 0.f;
    for (int r = lo + rr; r < hi; r += 2) acc += bf2f(h[(size_t)r * FDIM + j]);
    red[tid] = acc;
    __syncthreads();
    if (tid < 128) sp[tid] = (red[tid] + red[tid + 128]) / (float)max(cnt, 1);
    __syncthreads();

    if (tid < CDIM) {
        float l = bo[tid];
        for (int k = 0; k < 128; ++k) l += sp[k] * Wo[(size_t)k * CDIM + tid];
        lg[tid] = l;
    }
    __syncthreads();
    if (tid == 0) {
        float m = -1e30f;
        for (int c = 0; c < CDIM; ++c) m = fmaxf(m, lg[c]);
        float ssum = 0.f;
        for (int c = 0; c < CDIM; ++c) ssum += expf(lg[c] - m);
        sm[0] = m;
        sm[1] = logf(ssum);
    }
    __syncthreads();
    if (tid < CDIM) out[(size_t)g * CDIM + tid] = lg[tid] - sm[0] - sm[1];
}

// ---------------- launch ----------------

extern "C" void kernel_launch(void* const* d_in, const int* in_sizes, int n_in,
                              void* d_out, int out_size, void* d_ws, size_t ws_size,
                              hipStream_t stream) {
    const float* x = (const float*)d_in[0];
    const int* edge = (const int*)d_in[1];      // int32 (harness converts integer inputs)
    const int* batch = (const int*)d_in[2];     // int32
    const float* W1 = (const float*)d_in[4];
    const float* b1 = (const float*)d_in[5];
    const float* W2 = (const float*)d_in[6];
    const float* b2 = (const float*)d_in[7];
    const float* W3 = (const float*)d_in[8];
    const float* b3 = (const float*)d_in[9];
    const float* Wo = (const float*)d_in[10];
    const float* bo = (const float*)d_in[11];

    int N = in_sizes[2];
    int E = in_sizes[1] / 2;
    int G = out_size / CDIM;
    const int* src = edge;
    const int* dst = edge + E;
    int NB = (N + 255) >> 8;

    size_t off = 0;
    auto carve = [&](size_t bytes) -> size_t {
        size_t r = off;
        off += (bytes + 255) & ~(size_t)255;
        return r;
    };
    size_t o_aggb = carve((size_t)N * FDIM * 2);    // bf16
    size_t o_hbuf = carve((size_t)N * FDIM * 2);    // bf16; ebuf + xb alias here (both dead by gemm1)
    size_t o_colx = carve((size_t)E * 4);
    size_t o_rowp = carve((size_t)(N + 1) * 4);
    size_t o_dinv = carve((size_t)N * 4);
    size_t o_bcnt = carve((size_t)NB * 4);
    size_t o_boff = carve((size_t)(NB + 1) * 4);
    size_t o_bcur = carve((size_t)NB * 4);
    size_t o_wbt  = carve((size_t)3 * 16384 * 2);

    bool ok = off <= ws_size && NB <= 512 && N <= (1 << 24) &&
              (size_t)E * 4 <= (size_t)N * FDIM * 2;  // packed ebuf fits in hbuf alias
    if (!ok) {
        sentinel_kernel<<<(out_size + 255) / 256, 256, 0, stream>>>((float*)d_out, out_size, 1234.5f);
        return;
    }

    char* base = (char*)d_ws;
    u16* aggb  = (u16*)(base + o_aggb);
    u16* hbuf  = (u16*)(base + o_hbuf);
    unsigned* ebuf = (unsigned*)(base + o_hbuf);  // alias (dead after build_kernel)
    u16* xb    = (u16*)(base + o_hbuf);           // alias (written after build, dead after agg1)
    int* colx  = (int*)(base + o_colx);
    int* rowp  = (int*)(base + o_rowp);
    float* dinv = (float*)(base + o_dinv);
    int* bcnt  = (int*)(base + o_bcnt);
    int* boff  = (int*)(base + o_boff);
    int* bcur  = (int*)(base + o_bcur);
    u16* wbt   = (u16*)(base + o_wbt);

    int nchunk = (E + 4095) / 4096;

    wconv_kernel<<<192, 256, 0, stream>>>(W1, W2, W3, wbt);
    zero_kernel<<<1, 512, 0, stream>>>(bcnt, NB);
    count_kernel<<<nchunk, 256, 0, stream>>>(dst, E, bcnt, NB);
    scan_kernel<<<1, 512, 0, stream>>>(bcnt, NB, E, boff, bcur);
    part_kernel<<<nchunk, 256, 0, stream>>>(src, dst, E, bcur, ebuf, NB);
    build_kernel<<<NB, 256, 0, stream>>>(ebuf, boff, rowp, dinv, colx, N, E);
    xconv_kernel<<<(N * FDIM / 4 + 255) / 256, 256, 0, stream>>>(x, xb, N * FDIM);

    int aggBlocks = (N + 3) / 4;
    int gemmBlocks = (N + 63) / 64;

    agg_kernel<<<aggBlocks, 256, 0, stream>>>(xb, dinv, rowp, colx, aggb, N);
    gemm_mfma_kernel<<<gemmBlocks, 256, 0, stream>>>(aggb, wbt, b1, hbuf, N);
    agg_kernel<<<aggBlocks, 256, 0, stream>>>(hbuf, dinv, rowp, colx, aggb, N);
    gemm_mfma_kernel<<<gemmBlocks, 256, 0, stream>>>(aggb, wbt + 16384, b2, hbuf, N);
    agg_kernel<<<aggBlocks, 256, 0, stream>>>(hbuf, dinv, rowp, colx, aggb, N);
    gemm_mfma_kernel<<<gemmBlocks, 256, 0, stream>>>(aggb, wbt + 32768, b3, hbuf, N);

    pool_head_kernel<<<G, 256, 0, stream>>>(hbuf, batch, N, Wo, bo, (float*)d_out, G);
}